// Round 3
// baseline (1312.023 us; speedup 1.0000x reference)
//
#include <hip/hip_runtime.h>
#include <hip/hip_bf16.h>

// AttentionPoolingAdvance: B=8,S=2048,D=768.
// out[b] = mean_q softmax((Q K^T)/sqrt(D), key-mask) V
// Algebra: mean over q => out = sum_k c_k V_k, c_k=(1/S) sum_q w[q,k].
// score[q,k] == (z_q . x_k + beta_k)/sqrt(D) modulo row-constant terms that
// cancel in softmax, with z = x @ (Wq^T Wk), beta_k = x_k . (Wk^T bq).
// bk cancels entirely. V folds into out = (c^T x) Wv^T + bv.
//
// Input dtype (fp32 vs bf16) is detected ON DEVICE from x's bit patterns;
// all float inputs are normalized to bf16 copies in ws. Output dtype follows.

#define S 2048
#define DIM 768
#define BATCH 8

typedef __hip_bfloat16 bf16;
typedef __attribute__((ext_vector_type(8))) short bf16x8;
typedef __attribute__((ext_vector_type(4))) float f32x4;

__device__ __forceinline__ f32x4 mfma16(bf16x8 a, bf16x8 b, f32x4 c) {
  return __builtin_amdgcn_mfma_f32_16x16x32_bf16(a, b, c, 0, 0, 0);
}

#define INV_SCALE 0.03608439182435161f  // 1/sqrt(768)

// ---- dtype probe: bf16 N(0,1) halfwords have exp field in ~[115,130];
// fp32 mantissa halfwords are ~uniform -> certainly out of [96,158]. ----
__global__ __launch_bounds__(256) void detect_dtype(const unsigned short* __restrict__ x,
                                                    int* __restrict__ flag) {
  int bad = 0;
  for (int i = threadIdx.x; i < 2048; i += 256) {
    int e = (x[i] >> 7) & 0xFF;
    if (e < 0x60 || e >= 0x9F) bad = 1;
  }
  if (bad) atomicOr(flag, 1);  // 1 => fp32 inputs
}

// ---- normalize float input -> bf16 ws copy (8 elems/thread) ----
__global__ __launch_bounds__(256) void convert_bf16(const void* __restrict__ src,
                                                    bf16* __restrict__ dst,
                                                    long n, const int* __restrict__ flag) {
  long i = ((long)blockIdx.x * 256 + threadIdx.x) * 8;
  if (i >= n) return;
  if (*flag) {
    const float* s = (const float*)src + i;
#pragma unroll
    for (int j = 0; j < 8; ++j) dst[i + j] = __float2bfloat16(s[j]);
  } else {
    *(bf16x8*)((short*)dst + i) = *(const bf16x8*)((const short*)src + i);
  }
}

// ---- normalize float input -> fp32 ws copy (biases) ----
__global__ __launch_bounds__(256) void convert_f32(const void* __restrict__ src,
                                                   float* __restrict__ dst,
                                                   int n, const int* __restrict__ flag) {
  int i = blockIdx.x * 256 + threadIdx.x;
  if (i >= n) return;
  dst[i] = *flag ? ((const float*)src)[i]
                 : __bfloat162float(((const bf16*)src)[i]);
}

// ---- transpose Wq and Wk (768x768 bf16) ----
__global__ __launch_bounds__(256) void transpose2(const bf16* __restrict__ W0,
                                                  const bf16* __restrict__ W1,
                                                  bf16* __restrict__ T0,
                                                  bf16* __restrict__ T1) {
  __shared__ unsigned short tile[64][66];
  const unsigned short* src = (const unsigned short*)(blockIdx.z ? W1 : W0);
  unsigned short* dst = (unsigned short*)(blockIdx.z ? T1 : T0);
  const int obase = blockIdx.x * 64, ibase = blockIdx.y * 64;
  const int col = threadIdx.x & 63, rq = threadIdx.x >> 6;
#pragma unroll
  for (int rr = 0; rr < 64; rr += 4)
    tile[rr + rq][col] = src[(obase + rr + rq) * DIM + ibase + col];
  __syncthreads();
#pragma unroll
  for (int rr = 0; rr < 64; rr += 4)
    dst[(ibase + rr + rq) * DIM + obase + col] = tile[col][rr + rq];
}

// ---- generic NT gemm: D[m,n] = sum_k A[m,k]*B[n,k], ld=768, K=768 ----
__global__ __launch_bounds__(256) void gemm_nt_bf16(const bf16* __restrict__ A,
                                                    const bf16* __restrict__ Bm,
                                                    bf16* __restrict__ D) {
  const int wave = threadIdx.x >> 6, lane = threadIdx.x & 63;
  const int lr = lane & 15, quad = lane >> 4;
  const int mbase = blockIdx.x * 64 + wave * 16;
  const int nbase = blockIdx.y * 64;
  const short* a_row = (const short*)A + (long)(mbase + lr) * DIM + quad * 8;
  const short* b_row = (const short*)Bm + (long)(nbase + lr) * DIM + quad * 8;
  f32x4 acc[4] = {};
  for (int k = 0; k < DIM; k += 32) {
    bf16x8 a = *(const bf16x8*)(a_row + k);
#pragma unroll
    for (int t = 0; t < 4; ++t) {
      bf16x8 b = *(const bf16x8*)(b_row + (long)t * 16 * DIM + k);
      acc[t] = mfma16(a, b, acc[t]);
    }
  }
#pragma unroll
  for (int t = 0; t < 4; ++t)
#pragma unroll
    for (int r = 0; r < 4; ++r)
      D[(long)(mbase + quad * 4 + r) * DIM + nbase + t * 16 + lr] =
          __float2bfloat16(acc[t][r]);
}

// ---- bvec[j] = sum_o Wk[o,j]*bq[o] ----
__global__ __launch_bounds__(256) void bvec_kernel(const bf16* __restrict__ Wk,
                                                   const float* __restrict__ bq,
                                                   float* __restrict__ bvec) {
  const int j = blockIdx.x * 256 + threadIdx.x;
  float s = 0.f;
  for (int o = 0; o < DIM; ++o)
    s += __bfloat162float(Wk[(long)o * DIM + j]) * bq[o];
  bvec[j] = s;
}

// ---- betas[b,k] = mask ? (x_k . bvec)/sqrt(D) : -1e30 ----
__global__ __launch_bounds__(256) void beta_kernel(const bf16* __restrict__ x,
                                                   const int* __restrict__ mask,
                                                   const float* __restrict__ bvec,
                                                   float* __restrict__ betas) {
  const int wave = threadIdx.x >> 6, lane = threadIdx.x & 63;
  const int n = blockIdx.x * 4 + wave;  // [0, 16384)
  const bf16* xr = x + (long)n * DIM;
  float s = 0.f;
  for (int i = lane; i < DIM; i += 64) s += __bfloat162float(xr[i]) * bvec[i];
#pragma unroll
  for (int off = 1; off < 64; off <<= 1) s += __shfl_xor(s, off, 64);
  if (lane == 0) betas[n] = mask[n] ? s * INV_SCALE : -1e30f;
}

// ---- pass1: l[b,q] += sum_k exp(score) (split-k atomics) ----
__global__ __launch_bounds__(256) void pass1_l(const bf16* __restrict__ z,
                                               const bf16* __restrict__ x,
                                               const float* __restrict__ betas,
                                               float* __restrict__ l_out,
                                               int b0, int chunk) {
  const int wave = threadIdx.x >> 6, lane = threadIdx.x & 63;
  const int lr = lane & 15, quad = lane >> 4;
  const int lb = blockIdx.z, b = b0 + lb;
  const int q0 = blockIdx.x * 64 + wave * 16;
  const int kstart = blockIdx.y * chunk;
  const short* zrow = (const short*)z + (long)(lb * S + q0 + lr) * DIM + quad * 8;
  const short* xbase = (const short*)x + (long)b * S * DIM + quad * 8;
  const float* bet = betas + b * S;
  float lsum[4] = {0.f, 0.f, 0.f, 0.f};
  for (int kc = kstart; kc < kstart + chunk; kc += 64) {
    f32x4 acc[4] = {};
    const short* xrow = xbase + (long)(kc + lr) * DIM;
    for (int d = 0; d < DIM; d += 32) {
      bf16x8 a = *(const bf16x8*)(zrow + d);
#pragma unroll
      for (int t = 0; t < 4; ++t)
        acc[t] = mfma16(a, *(const bf16x8*)(xrow + (long)t * 16 * DIM + d), acc[t]);
    }
    float bs[4];
#pragma unroll
    for (int t = 0; t < 4; ++t) bs[t] = bet[kc + t * 16 + lr];
#pragma unroll
    for (int r = 0; r < 4; ++r) {
      float e = 0.f;
#pragma unroll
      for (int t = 0; t < 4; ++t)
        e += __expf(fminf(acc[t][r] * INV_SCALE + bs[t], 60.f));
      e += __shfl_xor(e, 1, 64);
      e += __shfl_xor(e, 2, 64);
      e += __shfl_xor(e, 4, 64);
      e += __shfl_xor(e, 8, 64);
      lsum[r] += e;
    }
  }
  if (lr == 0) {
#pragma unroll
    for (int r = 0; r < 4; ++r)
      atomicAdd(&l_out[b * S + q0 + quad * 4 + r], lsum[r]);
  }
}

// ---- pass2: c[b,k] += (1/S) sum_q exp(score)/l_q (split-q atomics) ----
__global__ __launch_bounds__(256) void pass2_c(const bf16* __restrict__ z,
                                               const bf16* __restrict__ x,
                                               const float* __restrict__ betas,
                                               const float* __restrict__ l_in,
                                               float* __restrict__ c_out,
                                               int b0, int chunk) {
  const int wave = threadIdx.x >> 6, lane = threadIdx.x & 63;
  const int lr = lane & 15, quad = lane >> 4;
  const int lb = blockIdx.z, b = b0 + lb;
  const int k0 = blockIdx.x * 64 + wave * 16;
  const int qstart = blockIdx.y * chunk;
  const short* xrow = (const short*)x + (long)(b * S + k0 + lr) * DIM + quad * 8;
  const short* zbase = (const short*)z + (long)lb * S * DIM + quad * 8;
  const float* li = l_in + b * S;
  float bsr[4];
#pragma unroll
  for (int r = 0; r < 4; ++r) bsr[r] = betas[b * S + k0 + quad * 4 + r];
  float csum[4] = {0.f, 0.f, 0.f, 0.f};
  for (int qc = qstart; qc < qstart + chunk; qc += 64) {
    f32x4 acc[4] = {};
    const short* zrow = zbase + (long)(qc + lr) * DIM;
    for (int d = 0; d < DIM; d += 32) {
      bf16x8 a = *(const bf16x8*)(xrow + d);
#pragma unroll
      for (int t = 0; t < 4; ++t)
        acc[t] = mfma16(a, *(const bf16x8*)(zrow + (long)t * 16 * DIM + d), acc[t]);
    }
    float rin[4];
#pragma unroll
    for (int t = 0; t < 4; ++t) {
      float lv = li[qc + t * 16 + lr];
      rin[t] = lv > 0.f ? 1.0f / lv : 0.f;
    }
#pragma unroll
    for (int r = 0; r < 4; ++r) {
      float e = 0.f;
#pragma unroll
      for (int t = 0; t < 4; ++t)
        e += __expf(fminf(acc[t][r] * INV_SCALE + bsr[r], 60.f)) * rin[t];
      e += __shfl_xor(e, 1, 64);
      e += __shfl_xor(e, 2, 64);
      e += __shfl_xor(e, 4, 64);
      e += __shfl_xor(e, 8, 64);
      csum[r] += e;
    }
  }
  if (lr == 0) {
#pragma unroll
    for (int r = 0; r < 4; ++r)
      atomicAdd(&c_out[b * S + k0 + quad * 4 + r], csum[r] * (1.0f / 2048.0f));
  }
}

// ---- y[b,i] = sum_k c[b,k]*x[b,k,i] (split-k atomics) ----
__global__ __launch_bounds__(256) void y_kernel(const bf16* __restrict__ x,
                                                const float* __restrict__ c,
                                                float* __restrict__ y) {
  const int b = blockIdx.z;
  const int i = blockIdx.x * 256 + threadIdx.x;
  const int kstart = blockIdx.y * 256;
  const bf16* xb = x + (long)(b * S + kstart) * DIM + i;
  const float* cb = c + b * S + kstart;
  float acc = 0.f;
  for (int k = 0; k < 256; ++k)
    acc += cb[k] * __bfloat162float(xb[(long)k * DIM]);
  atomicAdd(&y[b * DIM + i], acc);
}

// ---- out[b,o] = (y_b . Wv[o,:] + bv[o]), dtype per flag ----
__global__ __launch_bounds__(256) void out_kernel(const float* __restrict__ y,
                                                  const bf16* __restrict__ Wv,
                                                  const float* __restrict__ bv,
                                                  void* __restrict__ out,
                                                  const int* __restrict__ flag) {
  const int b = blockIdx.y;
  const int wave = threadIdx.x >> 6, lane = threadIdx.x & 63;
  const int obase = blockIdx.x * 64 + wave * 16;
  const float* yb = y + b * DIM;
  for (int oo = 0; oo < 16; ++oo) {
    const int o = obase + oo;
    const bf16* wr = Wv + (long)o * DIM;
    float s = 0.f;
    for (int i = lane; i < DIM; i += 64) s += yb[i] * __bfloat162float(wr[i]);
#pragma unroll
    for (int off = 1; off < 64; off <<= 1) s += __shfl_xor(s, off, 64);
    if (lane == 0) {
      float v = s + bv[o];
      if (*flag) ((float*)out)[b * DIM + o] = v;
      else ((bf16*)out)[b * DIM + o] = __float2bfloat16(v);
    }
  }
}

extern "C" void kernel_launch(void* const* d_in, const int* in_sizes, int n_in,
                              void* d_out, int out_size, void* d_ws, size_t ws_size,
                              hipStream_t stream) {
  const void* x_raw = d_in[0];
  const int* mask = (const int*)d_in[1];
  const void* Wq_raw = d_in[2];
  const void* bq_raw = d_in[3];
  const void* Wk_raw = d_in[4];
  // d_in[5] = bk: provably cancels out of the computation.
  const void* Wv_raw = d_in[6];
  const void* bv_raw = d_in[7];

  char* ws = (char*)d_ws;
  bf16* xb = (bf16*)(ws);                   //          0 .. 25,165,824
  bf16* Wqb = (bf16*)(ws + 25165824);       // 1,179,648 B
  bf16* Wkb = (bf16*)(ws + 26345472);       // 1,179,648 B
  bf16* Wvb = (bf16*)(ws + 27525120);       // 1,179,648 B
  bf16* WqT = (bf16*)(ws + 28704768);       // 1,179,648 B
  bf16* WkT = (bf16*)(ws + 29884416);       // 1,179,648 B
  bf16* Mt = (bf16*)(ws + 31064064);        // 1,179,648 B   Mt[j,i]=M[i,j]
  float* bqf = (float*)(ws + 32243712);     //     3,072 B
  float* bvf = (float*)(ws + 32246784);     //     3,072 B
  float* bvec = (float*)(ws + 32249856);    //     3,072 B
  float* betas = (float*)(ws + 32252928);   //    65,536 B
  float* l = (float*)(ws + 32318464);       //    65,536 B
  float* c = (float*)(ws + 32384000);       //    65,536 B
  float* y = (float*)(ws + 32449536);       //    24,576 B
  int* flag = (int*)(ws + 32474112);        //        64 B
  bf16* z = (bf16*)(ws + 32474176);         // nb * 3,145,728 B

  const size_t fixed = 32474176, zb = 3145728;
  int nb = 1;
  if (ws_size >= fixed + 8 * zb) nb = 8;
  else if (ws_size >= fixed + 4 * zb) nb = 4;
  else if (ws_size >= fixed + 2 * zb) nb = 2;
  const int rounds = BATCH / nb;
  const int nsplit = 32 / nb;
  const int chunk = S / nsplit;  // 64*nb

  // zero l, c, y, flag (contiguous)
  hipMemsetAsync(l, 0, 65536 + 65536 + 24576 + 64, stream);

  detect_dtype<<<1, 256, 0, stream>>>((const unsigned short*)x_raw, flag);
  convert_bf16<<<6144, 256, 0, stream>>>(x_raw, xb, (long)BATCH * S * DIM, flag);
  convert_bf16<<<288, 256, 0, stream>>>(Wq_raw, Wqb, (long)DIM * DIM, flag);
  convert_bf16<<<288, 256, 0, stream>>>(Wk_raw, Wkb, (long)DIM * DIM, flag);
  convert_bf16<<<288, 256, 0, stream>>>(Wv_raw, Wvb, (long)DIM * DIM, flag);
  convert_f32<<<3, 256, 0, stream>>>(bq_raw, bqf, DIM, flag);
  convert_f32<<<3, 256, 0, stream>>>(bv_raw, bvf, DIM, flag);

  transpose2<<<dim3(12, 12, 2), 256, 0, stream>>>(Wqb, Wkb, WqT, WkT);
  gemm_nt_bf16<<<dim3(12, 12), 256, 0, stream>>>(WkT, WqT, Mt);  // Mt = M^T
  bvec_kernel<<<3, 256, 0, stream>>>(Wkb, bqf, bvec);
  beta_kernel<<<4096, 256, 0, stream>>>(xb, mask, bvec, betas);

  for (int r = 0; r < rounds; ++r) {
    const int b0 = r * nb;
    gemm_nt_bf16<<<dim3(32 * nb, 12), 256, 0, stream>>>(
        xb + (long)b0 * S * DIM, Mt, z);  // z = x[b0..b0+nb) @ M
    pass1_l<<<dim3(32, nsplit, nb), 256, 0, stream>>>(z, xb, betas, l, b0, chunk);
    pass2_c<<<dim3(32, nsplit, nb), 256, 0, stream>>>(z, xb, betas, l, c, b0, chunk);
  }

  y_kernel<<<dim3(3, 8, 8), 256, 0, stream>>>(xb, c, y);
  out_kernel<<<dim3(12, 8), 256, 0, stream>>>(y, Wvb, bvf, d_out, flag);
}

// Round 5
// 410.776 us; speedup vs baseline: 3.1940x; 3.1940x over previous
//
#include <hip/hip_runtime.h>
#include <hip/hip_bf16.h>

// AttentionPoolingAdvance: B=8,S=2048,D=768 (fp32 in/out, detected on device).
// out[b] = mean_q softmax((Q K^T)/sqrt(D), key-mask) V
// Algebra: out = (c^T x) Wv^T + bv with c_k=(1/S) sum_q w[q,k];
// score[q,k] == (z_q.x_k)/sqrt(D) + beta_k modulo softmax-invariant terms,
// z = x @ (Wq^T Wk), beta_k = x_k.(Wk^T bq)/sqrt(D); bk cancels.
// Round 5: fix bf16 store (no .data member); E=exp(score) materialized bf16
// by m97-style tiled score GEMM; pass2 GEMM replaced by memory-bound reduce.

#define S 2048
#define DIM 768
#define BATCH 8

typedef __hip_bfloat16 bf16;
typedef __attribute__((ext_vector_type(8))) short bf16x8;
typedef __attribute__((ext_vector_type(4))) float f32x4;

__device__ __forceinline__ f32x4 mfma16(bf16x8 a, bf16x8 b, f32x4 c) {
  return __builtin_amdgcn_mfma_f32_16x16x32_bf16(a, b, c, 0, 0, 0);
}

__device__ __forceinline__ void load_lds16(const short* g, short* l) {
  __builtin_amdgcn_global_load_lds(
      (const __attribute__((address_space(1))) unsigned int*)g,
      (__attribute__((address_space(3))) unsigned int*)l, 16, 0, 0);
}

__device__ __forceinline__ float b2f(short u) {
  union { float f; unsigned u; } v;
  v.u = ((unsigned)(unsigned short)u) << 16;
  return v.f;
}

#define INV_SCALE 0.03608439182435161f  // 1/sqrt(768)

// ---- dtype probe: bf16 N(0,1) halfwords have exp field in ~[115,130];
// fp32 mantissa halfwords are ~uniform -> flagged out of [96,159). ----
__global__ __launch_bounds__(256) void detect_dtype(const unsigned short* __restrict__ x,
                                                    int* __restrict__ flag) {
  int bad = 0;
  for (int i = threadIdx.x; i < 2048; i += 256) {
    int e = (x[i] >> 7) & 0xFF;
    if (e < 0x60 || e >= 0x9F) bad = 1;
  }
  if (bad) atomicOr(flag, 1);  // 1 => fp32 inputs
}

__global__ __launch_bounds__(256) void convert_bf16(const void* __restrict__ src,
                                                    bf16* __restrict__ dst,
                                                    long n, const int* __restrict__ flag) {
  long i = ((long)blockIdx.x * 256 + threadIdx.x) * 8;
  if (i >= n) return;
  if (*flag) {
    const float* s = (const float*)src + i;
#pragma unroll
    for (int j = 0; j < 8; ++j) dst[i + j] = __float2bfloat16(s[j]);
  } else {
    *(bf16x8*)((short*)dst + i) = *(const bf16x8*)((const short*)src + i);
  }
}

__global__ __launch_bounds__(256) void convert_f32(const void* __restrict__ src,
                                                   float* __restrict__ dst,
                                                   int n, const int* __restrict__ flag) {
  int i = blockIdx.x * 256 + threadIdx.x;
  if (i >= n) return;
  dst[i] = *flag ? ((const float*)src)[i]
                 : __bfloat162float(((const bf16*)src)[i]);
}

// ---- transpose Wq and Wk (768x768 bf16) ----
__global__ __launch_bounds__(256) void transpose2(const bf16* __restrict__ W0,
                                                  const bf16* __restrict__ W1,
                                                  bf16* __restrict__ T0,
                                                  bf16* __restrict__ T1) {
  __shared__ unsigned short tile[64][66];
  const unsigned short* src = (const unsigned short*)(blockIdx.z ? W1 : W0);
  unsigned short* dst = (unsigned short*)(blockIdx.z ? T1 : T0);
  const int obase = blockIdx.x * 64, ibase = blockIdx.y * 64;
  const int col = threadIdx.x & 63, rq = threadIdx.x >> 6;
#pragma unroll
  for (int rr = 0; rr < 64; rr += 4)
    tile[rr + rq][col] = src[(obase + rr + rq) * DIM + ibase + col];
  __syncthreads();
#pragma unroll
  for (int rr = 0; rr < 64; rr += 4)
    dst[(ibase + rr + rq) * DIM + obase + col] = tile[col][rr + rq];
}

// ================= m97-style tiled NT GEMM core =================
// 128x128 C-tile per 256-thread block (4 waves, 2x2), BK=32, K=768,
// A,B row-major ld=768. Staging via global_load_lds width 16.
#define TILE_DECLS                                                          \
  __shared__ short As[4096], Bs[4096];                                      \
  const int tid = threadIdx.x;                                              \
  const int wave = tid >> 6, lane = tid & 63;                               \
  const int lr = lane & 15, quad = lane >> 4;                               \
  const int wm = (wave >> 1) * 64, wn = (wave & 1) * 64;                    \
  const int c0row = tid >> 2, colw = (tid & 3) * 8;

#define TILE_KLOOP(Abase, Bbase)                                            \
  const short* Ag0 = (Abase) + (long)(mblk + c0row) * DIM + colw;           \
  const short* Ag1 = (Abase) + (long)(mblk + 64 + c0row) * DIM + colw;      \
  const short* Bg0 = (Bbase) + (long)(nblk + c0row) * DIM + colw;           \
  const short* Bg1 = (Bbase) + (long)(nblk + 64 + c0row) * DIM + colw;      \
  short* Al0 = As + tid * 8;                                                \
  short* Al1 = As + 2048 + tid * 8;                                         \
  short* Bl0 = Bs + tid * 8;                                                \
  short* Bl1 = Bs + 2048 + tid * 8;                                         \
  f32x4 acc[4][4] = {};                                                     \
  for (int k0 = 0; k0 < DIM; k0 += 32) {                                    \
    load_lds16(Ag0 + k0, Al0);                                              \
    load_lds16(Ag1 + k0, Al1);                                              \
    load_lds16(Bg0 + k0, Bl0);                                              \
    load_lds16(Bg1 + k0, Bl1);                                              \
    asm volatile("s_waitcnt vmcnt(0)" ::: "memory");                        \
    __syncthreads();                                                        \
    bf16x8 af[4], bfr[4];                                                   \
    _Pragma("unroll") for (int it = 0; it < 4; ++it)                        \
        af[it] = *(const bf16x8*)(As + (wm + it * 16 + lr) * 32 + quad * 8);\
    _Pragma("unroll") for (int jt = 0; jt < 4; ++jt)                        \
        bfr[jt] = *(const bf16x8*)(Bs + (wn + jt * 16 + lr) * 32 + quad * 8);\
    _Pragma("unroll") for (int it = 0; it < 4; ++it)                        \
        _Pragma("unroll") for (int jt = 0; jt < 4; ++jt)                    \
            acc[it][jt] = mfma16(af[it], bfr[jt], acc[it][jt]);             \
    __syncthreads();                                                        \
  }

// ---- plain bf16-output tiled NT GEMM: D[m,n] = sum_k A[m,k]B[n,k] ----
__global__ __launch_bounds__(256) void gemm_nt_tiled(const bf16* __restrict__ A,
                                                     const bf16* __restrict__ B,
                                                     bf16* __restrict__ D) {
  const int mblk = blockIdx.x * 128, nblk = blockIdx.y * 128;
  TILE_DECLS
  TILE_KLOOP((const short*)A, (const short*)B)
#pragma unroll
  for (int it = 0; it < 4; ++it)
#pragma unroll
    for (int jt = 0; jt < 4; ++jt)
#pragma unroll
      for (int r = 0; r < 4; ++r)
        D[(long)(mblk + wm + it * 16 + quad * 4 + r) * DIM +
          nblk + wn + jt * 16 + lr] = __float2bfloat16(acc[it][jt][r]);
}

// ---- score GEMM: E[q,k]=exp(z_q.x_k*IS+beta_k) (bf16), l[q]+=rowsum ----
// grid (16,16,nb); blockIdx.z = local batch lb, global b = b0+lb.
__global__ __launch_bounds__(256) void gemm_score(const bf16* __restrict__ z,
                                                  const bf16* __restrict__ x,
                                                  const float* __restrict__ betas,
                                                  float* __restrict__ l_out,
                                                  bf16* __restrict__ E,
                                                  int b0) {
  const int mblk = blockIdx.x * 128, nblk = blockIdx.y * 128;
  const int lb = blockIdx.z, b = b0 + lb;
  TILE_DECLS
  TILE_KLOOP((const short*)z + (long)lb * S * DIM,
             (const short*)x + (long)b * S * DIM)
  float bet[4];
#pragma unroll
  for (int jt = 0; jt < 4; ++jt)
    bet[jt] = betas[b * S + nblk + wn + jt * 16 + lr];
  bf16* Eb = E + (long)lb * S * S;
  float* lrow = l_out + b * S;
#pragma unroll
  for (int it = 0; it < 4; ++it) {
#pragma unroll
    for (int r = 0; r < 4; ++r) {
      const int q = mblk + wm + it * 16 + quad * 4 + r;
      float s = 0.f;
#pragma unroll
      for (int jt = 0; jt < 4; ++jt) {
        float e = __expf(fminf(acc[it][jt][r] * INV_SCALE + bet[jt], 60.f));
        s += e;
        Eb[(long)q * S + nblk + wn + jt * 16 + lr] = __float2bfloat16(e);
      }
      s += __shfl_xor(s, 1, 64);
      s += __shfl_xor(s, 2, 64);
      s += __shfl_xor(s, 4, 64);
      s += __shfl_xor(s, 8, 64);
      if (lr == 0) atomicAdd(&lrow[q], s);
    }
  }
}

// ---- bvec[j] = sum_o Wk[o,j]*bq[o] ----
__global__ __launch_bounds__(256) void bvec_kernel(const bf16* __restrict__ Wk,
                                                   const float* __restrict__ bq,
                                                   float* __restrict__ bvec) {
  const int j = blockIdx.x * 256 + threadIdx.x;
  float s = 0.f;
  for (int o = 0; o < DIM; ++o)
    s += __bfloat162float(Wk[(long)o * DIM + j]) * bq[o];
  bvec[j] = s;
}

// ---- betas[b,k] = mask ? (x_k . bvec)/sqrt(D) : -1e30 ----
__global__ __launch_bounds__(256) void beta_kernel(const bf16* __restrict__ x,
                                                   const int* __restrict__ mask,
                                                   const float* __restrict__ bvec,
                                                   float* __restrict__ betas) {
  const int wave = threadIdx.x >> 6, lane = threadIdx.x & 63;
  const int n = blockIdx.x * 4 + wave;  // [0, 16384)
  const bf16* xr = x + (long)n * DIM;
  float s = 0.f;
  for (int i = lane; i < DIM; i += 64) s += __bfloat162float(xr[i]) * bvec[i];
#pragma unroll
  for (int off = 1; off < 64; off <<= 1) s += __shfl_xor(s, off, 64);
  if (lane == 0) betas[n] = mask[n] ? s * INV_SCALE : -1e30f;
}

// ---- l -> 1/l for batches [b0, b0+nb) ----
__global__ __launch_bounds__(256) void recip_range(float* __restrict__ l, int b0) {
  const int i = b0 * S + blockIdx.x * 256 + threadIdx.x;
  float v = l[i];
  l[i] = v > 0.f ? 1.0f / v : 0.f;
}

// ---- c[b,k] += (1/S) sum_q E[q,k] * linv[q]; grid (S/64, nb) ----
__global__ __launch_bounds__(256) void reduce_c(const bf16* __restrict__ E,
                                                const float* __restrict__ linv,
                                                float* __restrict__ c, int b0) {
  const int lb = blockIdx.y, b = b0 + lb;
  const int q0 = blockIdx.x * 64;
  const int k8 = threadIdx.x * 8;
  const short* Eb = (const short*)E + (long)lb * S * S + k8;
  const float* li = linv + b * S;
  float acc[8] = {};
  for (int q = q0; q < q0 + 64; ++q) {
    bf16x8 ev = *(const bf16x8*)(Eb + (long)q * S);
    const float rq = li[q];
#pragma unroll
    for (int j = 0; j < 8; ++j) acc[j] += b2f(ev[j]) * rq;
  }
#pragma unroll
  for (int j = 0; j < 8; ++j)
    atomicAdd(&c[b * S + k8 + j], acc[j] * (1.0f / 2048.0f));
}

// ---- y[b,i] = sum_k c[b,k]*x[b,k,i] (split-k atomics) ----
__global__ __launch_bounds__(256) void y_kernel(const bf16* __restrict__ x,
                                                const float* __restrict__ c,
                                                float* __restrict__ y) {
  const int b = blockIdx.z;
  const int i = blockIdx.x * 256 + threadIdx.x;
  const int kstart = blockIdx.y * 256;
  const bf16* xb = x + (long)(b * S + kstart) * DIM + i;
  const float* cb = c + b * S + kstart;
  float acc = 0.f;
  for (int k = 0; k < 256; ++k)
    acc += cb[k] * __bfloat162float(xb[(long)k * DIM]);
  atomicAdd(&y[b * DIM + i], acc);
}

// ---- out[b,o] = (y_b . Wv[o,:] + bv[o]), dtype per flag ----
__global__ __launch_bounds__(256) void out_kernel(const float* __restrict__ y,
                                                  const bf16* __restrict__ Wv,
                                                  const float* __restrict__ bv,
                                                  void* __restrict__ out,
                                                  const int* __restrict__ flag) {
  const int b = blockIdx.y;
  const int wave = threadIdx.x >> 6, lane = threadIdx.x & 63;
  const int obase = blockIdx.x * 64 + wave * 16;
  const float* yb = y + b * DIM;
  for (int oo = 0; oo < 16; ++oo) {
    const int o = obase + oo;
    const bf16* wr = Wv + (long)o * DIM;
    float s = 0.f;
    for (int i = lane; i < DIM; i += 64) s += yb[i] * __bfloat162float(wr[i]);
#pragma unroll
    for (int off = 1; off < 64; off <<= 1) s += __shfl_xor(s, off, 64);
    if (lane == 0) {
      float v = s + bv[o];
      if (*flag) ((float*)out)[b * DIM + o] = v;
      else ((bf16*)out)[b * DIM + o] = __float2bfloat16(v);
    }
  }
}

extern "C" void kernel_launch(void* const* d_in, const int* in_sizes, int n_in,
                              void* d_out, int out_size, void* d_ws, size_t ws_size,
                              hipStream_t stream) {
  const void* x_raw = d_in[0];
  const int* mask = (const int*)d_in[1];
  const void* Wq_raw = d_in[2];
  const void* bq_raw = d_in[3];
  const void* Wk_raw = d_in[4];
  // d_in[5] = bk: provably cancels out of the computation.
  const void* Wv_raw = d_in[6];
  const void* bv_raw = d_in[7];

  char* ws = (char*)d_ws;
  bf16* xb = (bf16*)(ws);                   //          0 .. 25,165,824
  bf16* Wqb = (bf16*)(ws + 25165824);
  bf16* Wkb = (bf16*)(ws + 26345472);
  bf16* Wvb = (bf16*)(ws + 27525120);
  bf16* WqT = (bf16*)(ws + 28704768);
  bf16* WkT = (bf16*)(ws + 29884416);
  bf16* Mt = (bf16*)(ws + 31064064);        // Mt[j,i] = M[i,j]
  float* bqf = (float*)(ws + 32243712);
  float* bvf = (float*)(ws + 32246784);
  float* bvec = (float*)(ws + 32249856);
  float* betas = (float*)(ws + 32252928);
  float* l = (float*)(ws + 32318464);
  float* c = (float*)(ws + 32384000);
  float* y = (float*)(ws + 32449536);
  int* flag = (int*)(ws + 32474112);
  bf16* z = (bf16*)(ws + 32474176);         // nb * 3,145,728 B

  const size_t fixed = 32474176;
  const size_t zb = 3145728, eb = 8388608;  // per-batch z / E bytes
  int nb = 1;
  if (ws_size >= fixed + 8 * (zb + eb)) nb = 8;
  else if (ws_size >= fixed + 4 * (zb + eb)) nb = 4;
  else if (ws_size >= fixed + 2 * (zb + eb)) nb = 2;
  bf16* E = (bf16*)(ws + fixed + (size_t)nb * zb);
  const int rounds = BATCH / nb;

  // zero l, c, y, flag (contiguous)
  (void)hipMemsetAsync(l, 0, 65536 + 65536 + 24576 + 64, stream);

  detect_dtype<<<1, 256, 0, stream>>>((const unsigned short*)x_raw, flag);
  convert_bf16<<<6144, 256, 0, stream>>>(x_raw, xb, (long)BATCH * S * DIM, flag);
  convert_bf16<<<288, 256, 0, stream>>>(Wq_raw, Wqb, (long)DIM * DIM, flag);
  convert_bf16<<<288, 256, 0, stream>>>(Wk_raw, Wkb, (long)DIM * DIM, flag);
  convert_bf16<<<288, 256, 0, stream>>>(Wv_raw, Wvb, (long)DIM * DIM, flag);
  convert_f32<<<3, 256, 0, stream>>>(bq_raw, bqf, DIM, flag);
  convert_f32<<<3, 256, 0, stream>>>(bv_raw, bvf, DIM, flag);

  transpose2<<<dim3(12, 12, 2), 256, 0, stream>>>(Wqb, Wkb, WqT, WkT);
  gemm_nt_tiled<<<dim3(6, 6), 256, 0, stream>>>(WkT, WqT, Mt);  // Mt = M^T
  bvec_kernel<<<3, 256, 0, stream>>>(Wkb, bqf, bvec);
  beta_kernel<<<4096, 256, 0, stream>>>(xb, mask, bvec, betas);

  for (int r = 0; r < rounds; ++r) {
    const int b0 = r * nb;
    // z[lb*S+q, :] = x[b0+lb, q, :] @ M
    gemm_nt_tiled<<<dim3(nb * 16, 6), 256, 0, stream>>>(
        xb + (long)b0 * S * DIM, Mt, z);
    gemm_score<<<dim3(16, 16, nb), 256, 0, stream>>>(z, xb, betas, l, E, b0);
    recip_range<<<nb * 8, 256, 0, stream>>>(l, b0);
    reduce_c<<<dim3(32, nb), 256, 0, stream>>>(E, l, c, b0);
  }

  y_kernel<<<dim3(3, 8, 8), 256, 0, stream>>>(xb, c, y);
  out_kernel<<<dim3(12, 8), 256, 0, stream>>>(y, Wvb, bvf, d_out, flag);
}

// Round 6
// 339.953 us; speedup vs baseline: 3.8594x; 1.2083x over previous
//
#include <hip/hip_runtime.h>
#include <hip/hip_bf16.h>

// AttentionPoolingAdvance: B=8,S=2048,D=768 (fp32 in/out, detected on device).
// out[b] = mean_q softmax((Q K^T)/sqrt(D), key-mask) V
// Algebra: out = (c^T x) Wv^T + bv with c_k=(1/S) sum_q w[q,k];
// score[q,k] == (z_q.x_k)/sqrt(D) + beta_k modulo softmax-invariant terms,
// z = x @ (Wq^T Wk), beta_k = x_k.(Wk^T bq)/sqrt(D); bk cancels.
// Round 6: dispatch-count 17 -> 11. Conversions fused into consumers
// (transpose/bvec/out read raw inputs), beta fused into x-convert, recip
// fused into reduce_c; fatter grids for the tail kernels.

#define S 2048
#define DIM 768
#define BATCH 8

typedef __hip_bfloat16 bf16;
typedef __attribute__((ext_vector_type(8))) short bf16x8;
typedef __attribute__((ext_vector_type(4))) float f32x4;

__device__ __forceinline__ f32x4 mfma16(bf16x8 a, bf16x8 b, f32x4 c) {
  return __builtin_amdgcn_mfma_f32_16x16x32_bf16(a, b, c, 0, 0, 0);
}

__device__ __forceinline__ void load_lds16(const short* g, short* l) {
  __builtin_amdgcn_global_load_lds(
      (const __attribute__((address_space(1))) unsigned int*)g,
      (__attribute__((address_space(3))) unsigned int*)l, 16, 0, 0);
}

__device__ __forceinline__ float b2f(short u) {
  union { float f; unsigned u; } v;
  v.u = ((unsigned)(unsigned short)u) << 16;
  return v.f;
}

__device__ __forceinline__ unsigned short f2b(float f) {
  bf16 h = __float2bfloat16(f);
  return *(unsigned short*)&h;
}

#define INV_SCALE 0.03608439182435161f  // 1/sqrt(768)

// ---- dtype probe: bf16 N(0,1) halfwords have exp field in ~[115,130];
// fp32 mantissa halfwords are ~uniform -> flagged out of [96,159). ----
__global__ __launch_bounds__(256) void detect_dtype(const unsigned short* __restrict__ x,
                                                    int* __restrict__ flag) {
  int bad = 0;
  for (int i = threadIdx.x; i < 2048; i += 256) {
    int e = (x[i] >> 7) & 0xFF;
    if (e < 0x60 || e >= 0x9F) bad = 1;
  }
  if (bad) atomicOr(flag, 1);  // 1 => fp32 inputs
}

// ---- transpose + dtype-normalize Wq and Wk (768x768 -> bf16 T) ----
__global__ __launch_bounds__(256) void transpose_conv(const void* __restrict__ W0,
                                                      const void* __restrict__ W1,
                                                      bf16* __restrict__ T0,
                                                      bf16* __restrict__ T1,
                                                      const int* __restrict__ flag) {
  __shared__ unsigned short tile[64][66];
  const void* src = blockIdx.z ? W1 : W0;
  unsigned short* dst = (unsigned short*)(blockIdx.z ? T1 : T0);
  const int f = *flag;
  const int obase = blockIdx.x * 64, ibase = blockIdx.y * 64;
  const int col = threadIdx.x & 63, rq = threadIdx.x >> 6;
#pragma unroll
  for (int rr = 0; rr < 64; rr += 4) {
    const long idx = (long)(obase + rr + rq) * DIM + ibase + col;
    const float v = f ? ((const float*)src)[idx] : b2f(((const short*)src)[idx]);
    tile[rr + rq][col] = f2b(v);
  }
  __syncthreads();
#pragma unroll
  for (int rr = 0; rr < 64; rr += 4)
    dst[(long)(ibase + rr + rq) * DIM + obase + col] = tile[col][rr + rq];
}

// ---- bvec[j] = sum_o Wk[o,j]*bq[o] (raw inputs) ----
__global__ __launch_bounds__(256) void bvec_kernel(const void* __restrict__ Wk_raw,
                                                   const void* __restrict__ bq_raw,
                                                   float* __restrict__ bvec,
                                                   const int* __restrict__ flag) {
  const int j = blockIdx.x * 256 + threadIdx.x;
  float s = 0.f;
  if (*flag) {
    const float* W = (const float*)Wk_raw;
    const float* bq = (const float*)bq_raw;
    for (int o = 0; o < DIM; ++o) s += W[(long)o * DIM + j] * bq[o];
  } else {
    const short* W = (const short*)Wk_raw;
    const short* bq = (const short*)bq_raw;
    for (int o = 0; o < DIM; ++o) s += b2f(W[(long)o * DIM + j]) * b2f(bq[o]);
  }
  bvec[j] = s;
}

// ---- fused: xb = bf16(x); betas[n] = mask ? (x_n.bvec)*IS : -1e30 ----
// grid 4096 x 256 (wave per row n in [0,16384))
__global__ __launch_bounds__(256) void convert_x_beta(const void* __restrict__ x_raw,
                                                      const int* __restrict__ mask,
                                                      const float* __restrict__ bvec,
                                                      bf16* __restrict__ xb,
                                                      float* __restrict__ betas,
                                                      const int* __restrict__ flag) {
  const int wave = threadIdx.x >> 6, lane = threadIdx.x & 63;
  const int n = blockIdx.x * 4 + wave;
  const int f = *flag;
  const float* x32 = (const float*)x_raw + (long)n * DIM;
  const short* x16 = (const short*)x_raw + (long)n * DIM;
  bf16* xo = xb + (long)n * DIM;
  float s = 0.f;
#pragma unroll
  for (int i = lane; i < DIM; i += 64) {
    const float v = f ? x32[i] : b2f(x16[i]);
    xo[i] = __float2bfloat16(v);
    s += v * bvec[i];
  }
#pragma unroll
  for (int off = 1; off < 64; off <<= 1) s += __shfl_xor(s, off, 64);
  if (lane == 0) betas[n] = mask[n] ? s * INV_SCALE : -1e30f;
}

// ================= m97-style tiled NT GEMM core =================
// 128x128 C-tile per 256-thread block (4 waves, 2x2), BK=32, K=768,
// A,B row-major ld=768. Staging via global_load_lds width 16.
#define TILE_DECLS                                                          \
  __shared__ short As[4096], Bs[4096];                                      \
  const int tid = threadIdx.x;                                              \
  const int wave = tid >> 6, lane = tid & 63;                               \
  const int lr = lane & 15, quad = lane >> 4;                               \
  const int wm = (wave >> 1) * 64, wn = (wave & 1) * 64;                    \
  const int c0row = tid >> 2, colw = (tid & 3) * 8;

#define TILE_KLOOP(Abase, Bbase)                                            \
  const short* Ag0 = (Abase) + (long)(mblk + c0row) * DIM + colw;           \
  const short* Ag1 = (Abase) + (long)(mblk + 64 + c0row) * DIM + colw;      \
  const short* Bg0 = (Bbase) + (long)(nblk + c0row) * DIM + colw;           \
  const short* Bg1 = (Bbase) + (long)(nblk + 64 + c0row) * DIM + colw;      \
  short* Al0 = As + tid * 8;                                                \
  short* Al1 = As + 2048 + tid * 8;                                         \
  short* Bl0 = Bs + tid * 8;                                                \
  short* Bl1 = Bs + 2048 + tid * 8;                                         \
  f32x4 acc[4][4] = {};                                                     \
  for (int k0 = 0; k0 < DIM; k0 += 32) {                                    \
    load_lds16(Ag0 + k0, Al0);                                              \
    load_lds16(Ag1 + k0, Al1);                                              \
    load_lds16(Bg0 + k0, Bl0);                                              \
    load_lds16(Bg1 + k0, Bl1);                                              \
    asm volatile("s_waitcnt vmcnt(0)" ::: "memory");                        \
    __syncthreads();                                                        \
    bf16x8 af[4], bfr[4];                                                   \
    _Pragma("unroll") for (int it = 0; it < 4; ++it)                        \
        af[it] = *(const bf16x8*)(As + (wm + it * 16 + lr) * 32 + quad * 8);\
    _Pragma("unroll") for (int jt = 0; jt < 4; ++jt)                        \
        bfr[jt] = *(const bf16x8*)(Bs + (wn + jt * 16 + lr) * 32 + quad * 8);\
    _Pragma("unroll") for (int it = 0; it < 4; ++it)                        \
        _Pragma("unroll") for (int jt = 0; jt < 4; ++jt)                    \
            acc[it][jt] = mfma16(af[it], bfr[jt], acc[it][jt]);             \
    __syncthreads();                                                        \
  }

// ---- plain bf16-output tiled NT GEMM: D[m,n] = sum_k A[m,k]B[n,k] ----
__global__ __launch_bounds__(256) void gemm_nt_tiled(const bf16* __restrict__ A,
                                                     const bf16* __restrict__ B,
                                                     bf16* __restrict__ D) {
  const int mblk = blockIdx.x * 128, nblk = blockIdx.y * 128;
  TILE_DECLS
  TILE_KLOOP((const short*)A, (const short*)B)
#pragma unroll
  for (int it = 0; it < 4; ++it)
#pragma unroll
    for (int jt = 0; jt < 4; ++jt)
#pragma unroll
      for (int r = 0; r < 4; ++r)
        D[(long)(mblk + wm + it * 16 + quad * 4 + r) * DIM +
          nblk + wn + jt * 16 + lr] = __float2bfloat16(acc[it][jt][r]);
}

// ---- score GEMM: E[q,k]=exp(z_q.x_k*IS+beta_k) (bf16), l[q]+=rowsum ----
// grid (16,16,nb); blockIdx.z = local batch lb, global b = b0+lb.
__global__ __launch_bounds__(256) void gemm_score(const bf16* __restrict__ z,
                                                  const bf16* __restrict__ x,
                                                  const float* __restrict__ betas,
                                                  float* __restrict__ l_out,
                                                  bf16* __restrict__ E,
                                                  int b0) {
  const int mblk = blockIdx.x * 128, nblk = blockIdx.y * 128;
  const int lb = blockIdx.z, b = b0 + lb;
  TILE_DECLS
  TILE_KLOOP((const short*)z + (long)lb * S * DIM,
             (const short*)x + (long)b * S * DIM)
  float bet[4];
#pragma unroll
  for (int jt = 0; jt < 4; ++jt)
    bet[jt] = betas[b * S + nblk + wn + jt * 16 + lr];
  bf16* Eb = E + (long)lb * S * S;
  float* lrow = l_out + b * S;
#pragma unroll
  for (int it = 0; it < 4; ++it) {
#pragma unroll
    for (int r = 0; r < 4; ++r) {
      const int q = mblk + wm + it * 16 + quad * 4 + r;
      float s = 0.f;
#pragma unroll
      for (int jt = 0; jt < 4; ++jt) {
        float e = __expf(fminf(acc[it][jt][r] * INV_SCALE + bet[jt], 60.f));
        s += e;
        Eb[(long)q * S + nblk + wn + jt * 16 + lr] = __float2bfloat16(e);
      }
      s += __shfl_xor(s, 1, 64);
      s += __shfl_xor(s, 2, 64);
      s += __shfl_xor(s, 4, 64);
      s += __shfl_xor(s, 8, 64);
      if (lr == 0) atomicAdd(&lrow[q], s);
    }
  }
}

// ---- c[b,k] += (1/S) sum_q E[q,k]/l[q]; grid (S/64, nb) ----
__global__ __launch_bounds__(256) void reduce_c(const bf16* __restrict__ E,
                                                const float* __restrict__ l,
                                                float* __restrict__ c, int b0) {
  const int lb = blockIdx.y, b = b0 + lb;
  const int q0 = blockIdx.x * 64;
  const int k8 = threadIdx.x * 8;
  const short* Eb = (const short*)E + (long)lb * S * S + k8;
  const float* lrow = l + b * S;
  float acc[8] = {};
  for (int q = q0; q < q0 + 64; ++q) {
    bf16x8 ev = *(const bf16x8*)(Eb + (long)q * S);
    const float lv = lrow[q];
    const float rq = lv > 0.f ? 1.0f / lv : 0.f;
#pragma unroll
    for (int j = 0; j < 8; ++j) acc[j] += b2f(ev[j]) * rq;
  }
#pragma unroll
  for (int j = 0; j < 8; ++j)
    atomicAdd(&c[b * S + k8 + j], acc[j] * (1.0f / 2048.0f));
}

// ---- y[b,i] = sum_k c[b,k]*x[b,k,i]; grid (3, 16, 8), k-chunk 128 ----
__global__ __launch_bounds__(256) void y_kernel(const bf16* __restrict__ x,
                                                const float* __restrict__ c,
                                                float* __restrict__ y) {
  const int b = blockIdx.z;
  const int i = blockIdx.x * 256 + threadIdx.x;
  const int kstart = blockIdx.y * 128;
  const bf16* xb = x + (long)(b * S + kstart) * DIM + i;
  const float* cb = c + b * S + kstart;
  float acc = 0.f;
  for (int k = 0; k < 128; ++k)
    acc += cb[k] * __bfloat162float(xb[(long)k * DIM]);
  atomicAdd(&y[b * DIM + i], acc);
}

// ---- out[b,o] = y_b . Wv[o,:] + bv[o] (raw Wv/bv, dtype per flag) ----
// grid 1536 x 256: one wave per (b,o) row.
__global__ __launch_bounds__(256) void out_kernel(const float* __restrict__ y,
                                                  const void* __restrict__ Wv_raw,
                                                  const void* __restrict__ bv_raw,
                                                  void* __restrict__ out,
                                                  const int* __restrict__ flag) {
  const int wave = threadIdx.x >> 6, lane = threadIdx.x & 63;
  const int w = blockIdx.x * 4 + wave;  // [0, 6144)
  const int b = w / DIM, o = w % DIM;
  const int f = *flag;
  const float* yb = y + b * DIM;
  float s = 0.f;
  if (f) {
    const float* wr = (const float*)Wv_raw + (long)o * DIM;
#pragma unroll
    for (int i = lane; i < DIM; i += 64) s += yb[i] * wr[i];
  } else {
    const short* wr = (const short*)Wv_raw + (long)o * DIM;
#pragma unroll
    for (int i = lane; i < DIM; i += 64) s += yb[i] * b2f(wr[i]);
  }
#pragma unroll
  for (int off = 1; off < 64; off <<= 1) s += __shfl_xor(s, off, 64);
  if (lane == 0) {
    const float bias = f ? ((const float*)bv_raw)[o] : b2f(((const short*)bv_raw)[o]);
    const float v = s + bias;
    if (f) ((float*)out)[b * DIM + o] = v;
    else ((bf16*)out)[b * DIM + o] = __float2bfloat16(v);
  }
}

extern "C" void kernel_launch(void* const* d_in, const int* in_sizes, int n_in,
                              void* d_out, int out_size, void* d_ws, size_t ws_size,
                              hipStream_t stream) {
  const void* x_raw = d_in[0];
  const int* mask = (const int*)d_in[1];
  const void* Wq_raw = d_in[2];
  const void* bq_raw = d_in[3];
  const void* Wk_raw = d_in[4];
  // d_in[5] = bk: provably cancels out of the computation.
  const void* Wv_raw = d_in[6];
  const void* bv_raw = d_in[7];

  char* ws = (char*)d_ws;
  bf16* xb = (bf16*)(ws);                   //          0 .. 25,165,824
  bf16* WqT = (bf16*)(ws + 25165824);       // 1,179,648 B
  bf16* WkT = (bf16*)(ws + 26345472);       // 1,179,648 B
  bf16* Mt = (bf16*)(ws + 27525120);        // 1,179,648 B  Mt[j,i]=M[i,j]
  float* bvec = (float*)(ws + 28704768);    //     3,072 B
  float* betas = (float*)(ws + 28707840);   //    65,536 B
  float* l = (float*)(ws + 28773376);       //    65,536 B
  float* c = (float*)(ws + 28838912);       //    65,536 B
  float* y = (float*)(ws + 28904448);       //    24,576 B
  int* flag = (int*)(ws + 28929024);        //        64 B
  bf16* z = (bf16*)(ws + 28929088);         // nb * 3,145,728 B

  const size_t fixed = 28929088;
  const size_t zb = 3145728, eb = 8388608;  // per-batch z / E bytes
  int nb = 1;
  if (ws_size >= fixed + 8 * (zb + eb)) nb = 8;
  else if (ws_size >= fixed + 4 * (zb + eb)) nb = 4;
  else if (ws_size >= fixed + 2 * (zb + eb)) nb = 2;
  bf16* E = (bf16*)(ws + fixed + (size_t)nb * zb);
  const int rounds = BATCH / nb;

  // zero l, c, y, flag (contiguous)
  (void)hipMemsetAsync(l, 0, 65536 + 65536 + 24576 + 64, stream);

  detect_dtype<<<1, 256, 0, stream>>>((const unsigned short*)x_raw, flag);
  transpose_conv<<<dim3(12, 12, 2), 256, 0, stream>>>(Wq_raw, Wk_raw, WqT, WkT, flag);
  bvec_kernel<<<3, 256, 0, stream>>>(Wk_raw, bq_raw, bvec, flag);
  gemm_nt_tiled<<<dim3(6, 6), 256, 0, stream>>>(WkT, WqT, Mt);  // Mt = M^T
  convert_x_beta<<<4096, 256, 0, stream>>>(x_raw, mask, bvec, xb, betas, flag);

  for (int r = 0; r < rounds; ++r) {
    const int b0 = r * nb;
    // z[lb*S+q, :] = x[b0+lb, q, :] @ M
    gemm_nt_tiled<<<dim3(nb * 16, 6), 256, 0, stream>>>(
        xb + (long)b0 * S * DIM, Mt, z);
    gemm_score<<<dim3(16, 16, nb), 256, 0, stream>>>(z, xb, betas, l, E, b0);
    reduce_c<<<dim3(32, nb), 256, 0, stream>>>(E, l, c, b0);
  }

  y_kernel<<<dim3(3, 16, 8), 256, 0, stream>>>(xb, c, y);
  out_kernel<<<1536, 256, 0, stream>>>(y, Wv_raw, bv_raw, d_out, flag);
}

// Round 7
// 331.593 us; speedup vs baseline: 3.9567x; 1.0252x over previous
//
#include <hip/hip_runtime.h>
#include <hip/hip_bf16.h>

// AttentionPoolingAdvance: B=8,S=2048,D=768 (fp32 in/out, detected on device).
// out[b] = mean_q softmax((Q K^T)/sqrt(D), key-mask) V
// Algebra: out = (c^T x) Wv^T + bv with c_k=(1/S) sum_q w[q,k];
// score[q,k] == (z_q.x_k)/sqrt(D) + beta_k modulo softmax-invariant terms,
// z = x @ (Wq^T Wk), beta_k = x_k.(Wk^T bq)/sqrt(D); bk cancels.
// Round 7: tail widened+fused. prep = transpose x2 + parallel bvec (1 launch);
// Mt-GEMM fused under vectorized x-convert+beta; reduce_c 4x blocks; out
// vectorized. 9 dispatches total.

#define S 2048
#define DIM 768
#define BATCH 8

typedef __hip_bfloat16 bf16;
typedef __attribute__((ext_vector_type(8))) short bf16x8;
typedef __attribute__((ext_vector_type(4))) short short4v;
typedef __attribute__((ext_vector_type(4))) float f32x4;

__device__ __forceinline__ f32x4 mfma16(bf16x8 a, bf16x8 b, f32x4 c) {
  return __builtin_amdgcn_mfma_f32_16x16x32_bf16(a, b, c, 0, 0, 0);
}

__device__ __forceinline__ void load_lds16(const short* g, short* l) {
  __builtin_amdgcn_global_load_lds(
      (const __attribute__((address_space(1))) unsigned int*)g,
      (__attribute__((address_space(3))) unsigned int*)l, 16, 0, 0);
}

__device__ __forceinline__ float b2f(short u) {
  union { float f; unsigned u; } v;
  v.u = ((unsigned)(unsigned short)u) << 16;
  return v.f;
}

__device__ __forceinline__ short f2b(float f) {
  bf16 h = __float2bfloat16(f);
  return *(short*)&h;
}

#define INV_SCALE 0.03608439182435161f  // 1/sqrt(768)

// ---- dtype probe: bf16 N(0,1) halfwords have exp field in ~[115,130];
// fp32 mantissa halfwords are ~uniform -> flagged out of [96,159). ----
__global__ __launch_bounds__(256) void detect_dtype(const unsigned short* __restrict__ x,
                                                    int* __restrict__ flag) {
  int bad = 0;
  for (int i = threadIdx.x; i < 2048; i += 256) {
    int e = (x[i] >> 7) & 0xFF;
    if (e < 0x60 || e >= 0x9F) bad = 1;
  }
  if (bad) atomicOr(flag, 1);  // 1 => fp32 inputs
}

// ---- prep: blocks 0..287 transpose Wq/Wk -> bf16 T; 288..293 bvec partials.
// bvec[j] = sum_o Wk[o,j]*bq[o]  (bvec pre-zeroed; atomic partial per chunk)
__global__ __launch_bounds__(256) void prep_kernel(const void* __restrict__ Wq_raw,
                                                   const void* __restrict__ Wk_raw,
                                                   const void* __restrict__ bq_raw,
                                                   bf16* __restrict__ T0,
                                                   bf16* __restrict__ T1,
                                                   float* __restrict__ bvec,
                                                   const int* __restrict__ flag) {
  const int f = *flag;
  const int bx = blockIdx.x;
  if (bx < 288) {
    __shared__ unsigned short tile[64][66];
    const int p = bx / 144, r = bx % 144;
    const void* src = p ? Wk_raw : Wq_raw;
    unsigned short* dst = (unsigned short*)(p ? T1 : T0);
    const int obase = (r / 12) * 64, ibase = (r % 12) * 64;
    const int col = threadIdx.x & 63, rq = threadIdx.x >> 6;
#pragma unroll
    for (int rr = 0; rr < 64; rr += 4) {
      const long idx = (long)(obase + rr + rq) * DIM + ibase + col;
      const float v = f ? ((const float*)src)[idx] : b2f(((const short*)src)[idx]);
      tile[rr + rq][col] = (unsigned short)f2b(v);
    }
    __syncthreads();
#pragma unroll
    for (int rr = 0; rr < 64; rr += 4)
      dst[(long)(ibase + rr + rq) * DIM + obase + col] = tile[col][rr + rq];
  } else {
    const int o0 = (bx - 288) * 128;
    const int t = threadIdx.x;
    float s0 = 0.f, s1 = 0.f, s2 = 0.f;
    if (f) {
      const float* W = (const float*)Wk_raw;
      const float* bq = (const float*)bq_raw;
      for (int o = o0; o < o0 + 128; ++o) {
        const float bo = bq[o];
        const float* row = W + (long)o * DIM;
        s0 += row[t] * bo;
        s1 += row[t + 256] * bo;
        s2 += row[t + 512] * bo;
      }
    } else {
      const short* W = (const short*)Wk_raw;
      const short* bq = (const short*)bq_raw;
      for (int o = o0; o < o0 + 128; ++o) {
        const float bo = b2f(bq[o]);
        const short* row = W + (long)o * DIM;
        s0 += b2f(row[t]) * bo;
        s1 += b2f(row[t + 256]) * bo;
        s2 += b2f(row[t + 512]) * bo;
      }
    }
    atomicAdd(&bvec[t], s0);
    atomicAdd(&bvec[t + 256], s1);
    atomicAdd(&bvec[t + 512], s2);
  }
}

// ================= m97-style tiled NT GEMM core =================
// 128x128 C-tile per 256-thread block (4 waves, 2x2), BK=32, K=768,
// A,B row-major ld=768. Staging via global_load_lds width 16.
#define TILE_DECLS                                                          \
  __shared__ short As[4096], Bs[4096];                                      \
  const int tid = threadIdx.x;                                              \
  const int wave = tid >> 6, lane = tid & 63;                               \
  const int lr = lane & 15, quad = lane >> 4;                               \
  const int wm = (wave >> 1) * 64, wn = (wave & 1) * 64;                    \
  const int c0row = tid >> 2, colw = (tid & 3) * 8;

#define TILE_KLOOP(Abase, Bbase)                                            \
  const short* Ag0 = (Abase) + (long)(mblk + c0row) * DIM + colw;           \
  const short* Ag1 = (Abase) + (long)(mblk + 64 + c0row) * DIM + colw;      \
  const short* Bg0 = (Bbase) + (long)(nblk + c0row) * DIM + colw;           \
  const short* Bg1 = (Bbase) + (long)(nblk + 64 + c0row) * DIM + colw;      \
  short* Al0 = As + tid * 8;                                                \
  short* Al1 = As + 2048 + tid * 8;                                         \
  short* Bl0 = Bs + tid * 8;                                                \
  short* Bl1 = Bs + 2048 + tid * 8;                                         \
  f32x4 acc[4][4] = {};                                                     \
  for (int k0 = 0; k0 < DIM; k0 += 32) {                                    \
    load_lds16(Ag0 + k0, Al0);                                              \
    load_lds16(Ag1 + k0, Al1);                                              \
    load_lds16(Bg0 + k0, Bl0);                                              \
    load_lds16(Bg1 + k0, Bl1);                                              \
    asm volatile("s_waitcnt vmcnt(0)" ::: "memory");                        \
    __syncthreads();                                                        \
    bf16x8 af[4], bfr[4];                                                   \
    _Pragma("unroll") for (int it = 0; it < 4; ++it)                        \
        af[it] = *(const bf16x8*)(As + (wm + it * 16 + lr) * 32 + quad * 8);\
    _Pragma("unroll") for (int jt = 0; jt < 4; ++jt)                        \
        bfr[jt] = *(const bf16x8*)(Bs + (wn + jt * 16 + lr) * 32 + quad * 8);\
    _Pragma("unroll") for (int it = 0; it < 4; ++it)                        \
        _Pragma("unroll") for (int jt = 0; jt < 4; ++jt)                    \
            acc[it][jt] = mfma16(af[it], bfr[jt], acc[it][jt]);             \
    __syncthreads();                                                        \
  }

// ---- plain bf16-output tiled NT GEMM: D[m,n] = sum_k A[m,k]B[n,k] ----
__global__ __launch_bounds__(256) void gemm_nt_tiled(const bf16* __restrict__ A,
                                                     const bf16* __restrict__ B,
                                                     bf16* __restrict__ D) {
  const int mblk = blockIdx.x * 128, nblk = blockIdx.y * 128;
  TILE_DECLS
  TILE_KLOOP((const short*)A, (const short*)B)
#pragma unroll
  for (int it = 0; it < 4; ++it)
#pragma unroll
    for (int jt = 0; jt < 4; ++jt)
#pragma unroll
      for (int r = 0; r < 4; ++r)
        D[(long)(mblk + wm + it * 16 + quad * 4 + r) * DIM +
          nblk + wn + jt * 16 + lr] = __float2bfloat16(acc[it][jt][r]);
}

// ---- fused: blocks 0..35 = Mt GEMM (Mt = (WqT)^T-style NT product);
// blocks 36..4131 = x-convert + beta (vectorized). ----
__global__ __launch_bounds__(256) void mt_convert(const bf16* __restrict__ WkT,
                                                  const bf16* __restrict__ WqT,
                                                  bf16* __restrict__ Mt,
                                                  const void* __restrict__ x_raw,
                                                  const int* __restrict__ mask,
                                                  const float* __restrict__ bvec,
                                                  bf16* __restrict__ xb,
                                                  float* __restrict__ betas,
                                                  const int* __restrict__ flag) {
  const int bx = blockIdx.x;
  if (bx < 36) {
    const int mblk = (bx / 6) * 128, nblk = (bx % 6) * 128;
    TILE_DECLS
    TILE_KLOOP((const short*)WkT, (const short*)WqT)
#pragma unroll
    for (int it = 0; it < 4; ++it)
#pragma unroll
      for (int jt = 0; jt < 4; ++jt)
#pragma unroll
        for (int r = 0; r < 4; ++r)
          Mt[(long)(mblk + wm + it * 16 + quad * 4 + r) * DIM +
             nblk + wn + jt * 16 + lr] = __float2bfloat16(acc[it][jt][r]);
  } else {
    const int wave = threadIdx.x >> 6, lane = threadIdx.x & 63;
    const int n = (bx - 36) * 4 + wave;  // [0, 16384)
    const int f = *flag;
    short* xo = (short*)xb + (long)n * DIM;
    float s = 0.f;
    if (f) {
      const float4* x4 = (const float4*)((const float*)x_raw + (long)n * DIM);
      const float4* bv4 = (const float4*)bvec;
#pragma unroll
      for (int it = 0; it < 3; ++it) {
        const int idx = it * 64 + lane;
        const float4 v = x4[idx];
        const float4 bb = bv4[idx];
        short4v sv = {f2b(v.x), f2b(v.y), f2b(v.z), f2b(v.w)};
        *(short4v*)(xo + idx * 4) = sv;
        s += v.x * bb.x + v.y * bb.y + v.z * bb.z + v.w * bb.w;
      }
    } else {
      const short4v* x4 = (const short4v*)((const short*)x_raw + (long)n * DIM);
      const float4* bv4 = (const float4*)bvec;
#pragma unroll
      for (int it = 0; it < 3; ++it) {
        const int idx = it * 64 + lane;
        const short4v v = x4[idx];
        const float4 bb = bv4[idx];
        *(short4v*)(xo + idx * 4) = v;
        s += b2f(v.x) * bb.x + b2f(v.y) * bb.y + b2f(v.z) * bb.z + b2f(v.w) * bb.w;
      }
    }
#pragma unroll
    for (int off = 1; off < 64; off <<= 1) s += __shfl_xor(s, off, 64);
    if (lane == 0) betas[n] = mask[n] ? s * INV_SCALE : -1e30f;
  }
}

// ---- score GEMM: E[q,k]=exp(z_q.x_k*IS+beta_k) (bf16), l[q]+=rowsum ----
// grid (16,16,nb); blockIdx.z = local batch lb, global b = b0+lb.
__global__ __launch_bounds__(256) void gemm_score(const bf16* __restrict__ z,
                                                  const bf16* __restrict__ x,
                                                  const float* __restrict__ betas,
                                                  float* __restrict__ l_out,
                                                  bf16* __restrict__ E,
                                                  int b0) {
  const int mblk = blockIdx.x * 128, nblk = blockIdx.y * 128;
  const int lb = blockIdx.z, b = b0 + lb;
  TILE_DECLS
  TILE_KLOOP((const short*)z + (long)lb * S * DIM,
             (const short*)x + (long)b * S * DIM)
  float bet[4];
#pragma unroll
  for (int jt = 0; jt < 4; ++jt)
    bet[jt] = betas[b * S + nblk + wn + jt * 16 + lr];
  bf16* Eb = E + (long)lb * S * S;
  float* lrow = l_out + b * S;
#pragma unroll
  for (int it = 0; it < 4; ++it) {
#pragma unroll
    for (int r = 0; r < 4; ++r) {
      const int q = mblk + wm + it * 16 + quad * 4 + r;
      float s = 0.f;
#pragma unroll
      for (int jt = 0; jt < 4; ++jt) {
        float e = __expf(fminf(acc[it][jt][r] * INV_SCALE + bet[jt], 60.f));
        s += e;
        Eb[(long)q * S + nblk + wn + jt * 16 + lr] = __float2bfloat16(e);
      }
      s += __shfl_xor(s, 1, 64);
      s += __shfl_xor(s, 2, 64);
      s += __shfl_xor(s, 4, 64);
      s += __shfl_xor(s, 8, 64);
      if (lr == 0) atomicAdd(&lrow[q], s);
    }
  }
}

// ---- c[b,k] += (1/S) sum_q E[q,k]/l[q]; grid (S/16, nb), 16 q-rows/block ----
__global__ __launch_bounds__(256) void reduce_c(const bf16* __restrict__ E,
                                                const float* __restrict__ l,
                                                float* __restrict__ c, int b0) {
  const int lb = blockIdx.y, b = b0 + lb;
  const int q0 = blockIdx.x * 16;
  const int k8 = threadIdx.x * 8;
  const short* Eb = (const short*)E + (long)lb * S * S + k8;
  const float* lrow = l + b * S;
  float acc[8] = {};
#pragma unroll
  for (int q = q0; q < q0 + 16; ++q) {
    bf16x8 ev = *(const bf16x8*)(Eb + (long)q * S);
    const float lv = lrow[q];
    const float rq = lv > 0.f ? 1.0f / lv : 0.f;
#pragma unroll
    for (int j = 0; j < 8; ++j) acc[j] += b2f(ev[j]) * rq;
  }
#pragma unroll
  for (int j = 0; j < 8; ++j)
    atomicAdd(&c[b * S + k8 + j], acc[j] * (1.0f / 2048.0f));
}

// ---- y[b,i] = sum_k c[b,k]*x[b,k,i]; grid (3, 16, 8), k-chunk 128 ----
__global__ __launch_bounds__(256) void y_kernel(const bf16* __restrict__ x,
                                                const float* __restrict__ c,
                                                float* __restrict__ y) {
  const int b = blockIdx.z;
  const int i = blockIdx.x * 256 + threadIdx.x;
  const int kstart = blockIdx.y * 128;
  const bf16* xb = x + (long)(b * S + kstart) * DIM + i;
  const float* cb = c + b * S + kstart;
  float acc = 0.f;
  for (int k = 0; k < 128; ++k)
    acc += cb[k] * __bfloat162float(xb[(long)k * DIM]);
  atomicAdd(&y[b * DIM + i], acc);
}

// ---- out[b,o] = y_b . Wv[o,:] + bv[o] (raw Wv/bv, dtype per flag) ----
// grid 1536 x 256: one wave per (b,o) row, vectorized.
__global__ __launch_bounds__(256) void out_kernel(const float* __restrict__ y,
                                                  const void* __restrict__ Wv_raw,
                                                  const void* __restrict__ bv_raw,
                                                  void* __restrict__ out,
                                                  const int* __restrict__ flag) {
  const int wave = threadIdx.x >> 6, lane = threadIdx.x & 63;
  const int w = blockIdx.x * 4 + wave;  // [0, 6144)
  const int b = w / DIM, o = w % DIM;
  const int f = *flag;
  const float4* y4 = (const float4*)(y + (long)b * DIM);
  float s = 0.f;
  if (f) {
    const float4* wr = (const float4*)((const float*)Wv_raw + (long)o * DIM);
#pragma unroll
    for (int it = 0; it < 3; ++it) {
      const int idx = it * 64 + lane;
      const float4 a = y4[idx], wv = wr[idx];
      s += a.x * wv.x + a.y * wv.y + a.z * wv.z + a.w * wv.w;
    }
  } else {
    const short4v* wr = (const short4v*)((const short*)Wv_raw + (long)o * DIM);
#pragma unroll
    for (int it = 0; it < 3; ++it) {
      const int idx = it * 64 + lane;
      const float4 a = y4[idx];
      const short4v wv = wr[idx];
      s += a.x * b2f(wv.x) + a.y * b2f(wv.y) + a.z * b2f(wv.z) + a.w * b2f(wv.w);
    }
  }
#pragma unroll
  for (int off = 1; off < 64; off <<= 1) s += __shfl_xor(s, off, 64);
  if (lane == 0) {
    const float bias = f ? ((const float*)bv_raw)[o] : b2f(((const short*)bv_raw)[o]);
    const float v = s + bias;
    if (f) ((float*)out)[b * DIM + o] = v;
    else ((bf16*)out)[b * DIM + o] = __float2bfloat16(v);
  }
}

extern "C" void kernel_launch(void* const* d_in, const int* in_sizes, int n_in,
                              void* d_out, int out_size, void* d_ws, size_t ws_size,
                              hipStream_t stream) {
  const void* x_raw = d_in[0];
  const int* mask = (const int*)d_in[1];
  const void* Wq_raw = d_in[2];
  const void* bq_raw = d_in[3];
  const void* Wk_raw = d_in[4];
  // d_in[5] = bk: provably cancels out of the computation.
  const void* Wv_raw = d_in[6];
  const void* bv_raw = d_in[7];

  char* ws = (char*)d_ws;
  bf16* xb = (bf16*)(ws);                   //          0 .. 25,165,824
  bf16* WqT = (bf16*)(ws + 25165824);       // 1,179,648 B
  bf16* WkT = (bf16*)(ws + 26345472);       // 1,179,648 B
  bf16* Mt = (bf16*)(ws + 27525120);        // 1,179,648 B  Mt[j,i]=M[i,j]
  float* betas = (float*)(ws + 28704768);   //    65,536 B
  // ---- zeroed region starts here ----
  float* bvec = (float*)(ws + 28770304);    //     3,072 B
  float* l = (float*)(ws + 28773376);       //    65,536 B
  float* c = (float*)(ws + 28838912);       //    65,536 B
  float* y = (float*)(ws + 28904448);       //    24,576 B
  int* flag = (int*)(ws + 28929024);        //        64 B
  bf16* z = (bf16*)(ws + 28929088);         // nb * 3,145,728 B

  const size_t fixed = 28929088;
  const size_t zb = 3145728, eb = 8388608;  // per-batch z / E bytes
  int nb = 1;
  if (ws_size >= fixed + 8 * (zb + eb)) nb = 8;
  else if (ws_size >= fixed + 4 * (zb + eb)) nb = 4;
  else if (ws_size >= fixed + 2 * (zb + eb)) nb = 2;
  bf16* E = (bf16*)(ws + fixed + (size_t)nb * zb);
  const int rounds = BATCH / nb;

  // zero bvec, l, c, y, flag (contiguous)
  (void)hipMemsetAsync(bvec, 0, 3072 + 65536 + 65536 + 24576 + 64, stream);

  detect_dtype<<<1, 256, 0, stream>>>((const unsigned short*)x_raw, flag);
  prep_kernel<<<294, 256, 0, stream>>>(Wq_raw, Wk_raw, bq_raw, WqT, WkT, bvec, flag);
  mt_convert<<<4132, 256, 0, stream>>>(WkT, WqT, Mt, x_raw, mask, bvec, xb,
                                       betas, flag);

  for (int r = 0; r < rounds; ++r) {
    const int b0 = r * nb;
    // z[lb*S+q, :] = x[b0+lb, q, :] @ M
    gemm_nt_tiled<<<dim3(nb * 16, 6), 256, 0, stream>>>(
        xb + (long)b0 * S * DIM, Mt, z);
    gemm_score<<<dim3(16, 16, nb), 256, 0, stream>>>(z, xb, betas, l, E, b0);
    reduce_c<<<dim3(128, nb), 256, 0, stream>>>(E, l, c, b0);
  }

  y_kernel<<<dim3(3, 16, 8), 256, 0, stream>>>(xb, c, y);
  out_kernel<<<1536, 256, 0, stream>>>(y, Wv_raw, bv_raw, d_out, flag);
}